// Round 1
// baseline (205.691 us; speedup 1.0000x reference)
//
#include <hip/hip_runtime.h>

#define EPS 1e-5f
#define TEMP 50.0f
#define CCH 64
#define HH 128
#define WW 128
#define HWSZ (HH * WW)
#define CEPS2 (CCH * EPS * EPS)

// Pre-pass: per-pixel raw sum s = sum_c x, and raw sumsq q = sum_c x^2.
__global__ __launch_bounds__(256) void rv_norms(const float* __restrict__ x,
                                                float* __restrict__ s_out,
                                                float* __restrict__ q_out) {
    int p = blockIdx.x * 256 + threadIdx.x;      // 0 .. 4*HW-1
    int b = p >> 14;                              // HW = 16384 = 2^14
    int hw = p & (HWSZ - 1);
    const float* base = x + (size_t)b * (CCH * HWSZ) + hw;
    float s = 0.f, q = 0.f;
#pragma unroll
    for (int c = 0; c < CCH; ++c) {
        float v = base[c * HWSZ];
        s += v;
        q = fmaf(v, v, q);
    }
    s_out[p] = s;
    q_out[p] = q;
}

// Main: one thread per pixel. lane = w (coalesced). Two passes over channels.
__global__ __launch_bounds__(256) void rv_main(const float* __restrict__ x,
                                               const float* __restrict__ s_arr,
                                               const float* __restrict__ q_arr,
                                               float* __restrict__ out) {
    const int w = blockIdx.x * 64 + (int)threadIdx.x;   // 0..127
    const int h = blockIdx.y * 4 + (int)threadIdx.y;    // 0..127
    const int b = blockIdx.z;
    const float* xb = x + (size_t)b * (CCH * HWSZ);

    int hoff[5], woff[5];
    bool hin[5], win[5];
#pragma unroll
    for (int d = 0; d < 5; ++d) {
        int hh2 = h + d - 2;
        hin[d] = (hh2 >= 0) && (hh2 < HH);
        int hc = hh2 < 0 ? 0 : (hh2 > HH - 1 ? HH - 1 : hh2);
        hoff[d] = hc * WW;
        int ww2 = w + d - 2;
        win[d] = (ww2 >= 0) && (ww2 < WW);
        woff[d] = ww2 < 0 ? 0 : (ww2 > WW - 1 ? WW - 1 : ww2);
    }

    float D[25];
#pragma unroll
    for (int n = 0; n < 25; ++n) D[n] = 0.f;

    // ---- Pass 1: raw dot products against the 25 (clamped) neighbors ----
#pragma unroll 4
    for (int c = 0; c < CCH; ++c) {
        const float* pc = xb + c * HWSZ;
        float nb[25];
#pragma unroll
        for (int di = 0; di < 5; ++di) {
            const float* r = pc + hoff[di];
#pragma unroll
            for (int dj = 0; dj < 5; ++dj) {
                nb[di * 5 + dj] = r[woff[dj]];
            }
        }
        float cv = nb[12];   // center (h,w) is always in-bounds
#pragma unroll
        for (int n = 0; n < 25; ++n) {
            D[n] = fmaf(cv, nb[n], D[n]);
        }
    }

    const int p = b * HWSZ + h * WW + w;
    const float s_p = s_arr[p];
    const float q_p = q_arr[p];
    const float N2c = fmaf(2.f * EPS, s_p, q_p) + CEPS2;

    // ---- Similarities -> logits ----
    float logit[25];
    float m = -1e30f;
#pragma unroll
    for (int di = 0; di < 5; ++di) {
#pragma unroll
        for (int dj = 0; dj < 5; ++dj) {
            const int n = di * 5 + dj;
            const bool inb = hin[di] && win[dj];
            const int qi = b * HWSZ + hoff[di] + woff[dj];  // clamped, valid
            const float s_q = inb ? s_arr[qi] : 0.f;
            const float q_q = inb ? q_arr[qi] : 0.f;
            const float Dn = (inb ? D[n] : 0.f) + EPS * (s_p + s_q) + CEPS2;
            const float N2n = fmaf(2.f * EPS, s_q, q_q) + CEPS2;
            const float sim = Dn * rsqrtf(N2n * N2c);
            const float t = TEMP * sim;
            logit[n] = t;
            m = fmaxf(m, t);
        }
    }

    // ---- Softmax over 25 neighbors ----
    float wei[25];
    float sum = 0.f;
#pragma unroll
    for (int n = 0; n < 25; ++n) {
        float e = __expf(logit[n] - m);
        wei[n] = e;
        sum += e;
    }
    const float rs = 1.f / sum;
    // Zero weights of OOB neighbors: their entire contribution is the
    // EPS*sum(wei)=EPS constant folded into the accumulator init below.
#pragma unroll
    for (int di = 0; di < 5; ++di) {
#pragma unroll
        for (int dj = 0; dj < 5; ++dj) {
            const int n = di * 5 + dj;
            wei[n] = (hin[di] && win[dj]) ? wei[n] * rs : 0.f;
        }
    }

    // ---- Pass 2: weighted sum per channel ----
#pragma unroll 4
    for (int c = 0; c < CCH; ++c) {
        const float* pc = xb + c * HWSZ;
        float acc = EPS;
#pragma unroll
        for (int di = 0; di < 5; ++di) {
            const float* r = pc + hoff[di];
#pragma unroll
            for (int dj = 0; dj < 5; ++dj) {
                acc = fmaf(wei[di * 5 + dj], r[woff[dj]], acc);
            }
        }
        out[((size_t)b * CCH + c) * HWSZ + h * WW + w] = acc;
    }
}

extern "C" void kernel_launch(void* const* d_in, const int* in_sizes, int n_in,
                              void* d_out, int out_size, void* d_ws, size_t ws_size,
                              hipStream_t stream) {
    const float* x = (const float*)d_in[0];
    float* outp = (float*)d_out;
    float* s_arr = (float*)d_ws;
    float* q_arr = s_arr + 4 * HWSZ;

    rv_norms<<<dim3((4 * HWSZ) / 256), dim3(256), 0, stream>>>(x, s_arr, q_arr);
    rv_main<<<dim3(WW / 64, HH / 4, 4), dim3(64, 4, 1), 0, stream>>>(x, s_arr, q_arr, outp);
}

// Round 2
// 176.019 us; speedup vs baseline: 1.1686x; 1.1686x over previous
//
#include <hip/hip_runtime.h>

#define EPS 1e-5f
#define TEMP 50.0f
#define CCH 64
#define HH 128
#define WW 128
#define HWSZ (HH * WW)
#define CEPS2 (CCH * EPS * EPS)

// Pre-pass: per-pixel raw sum s = sum_c x and sumsq q = sum_c x^2.
// Block: 64 w-lanes x 4 channel-groups (16 ch each), LDS reduce.
__global__ __launch_bounds__(256) void rv_norms(const float* __restrict__ x,
                                                float* __restrict__ s_out,
                                                float* __restrict__ q_out) {
    const int lane = threadIdx.x;        // 0..63  (w within 64-tile)
    const int cg   = threadIdx.y;        // 0..3   (channel group)
    const int w = blockIdx.x * 64 + lane;
    const int h = blockIdx.y;
    const int b = blockIdx.z;

    const float* base = x + (size_t)b * (CCH * HWSZ) + (size_t)(cg * 16) * HWSZ + h * WW + w;
    float s = 0.f, q = 0.f;
#pragma unroll
    for (int c = 0; c < 16; ++c) {
        float v = base[c * HWSZ];
        s += v;
        q = fmaf(v, v, q);
    }
    __shared__ float rs[4][64];
    __shared__ float rq[4][64];
    rs[cg][lane] = s;
    rq[cg][lane] = q;
    __syncthreads();
    if (cg == 0) {
        s = rs[0][lane] + rs[1][lane] + rs[2][lane] + rs[3][lane];
        q = rq[0][lane] + rq[1][lane] + rq[2][lane] + rq[3][lane];
        const int p = b * HWSZ + h * WW + w;
        s_out[p] = s;
        q_out[p] = q;
    }
}

// Fused main. Block: 64 w-lanes x 4 channel-groups. One h-row of 64 w per block.
// Phase 1: partial dots over 16 channels, LDS reduce, softmax by cg==0.
// Phase 2: all threads apply weights to their 16 channels.
__global__ __launch_bounds__(256, 4) void rv_fused(const float* __restrict__ x,
                                                   const float* __restrict__ s_arr,
                                                   const float* __restrict__ q_arr,
                                                   float* __restrict__ out) {
    const int lane = threadIdx.x;            // w within tile
    const int cg   = threadIdx.y;            // channel group
    const int w = blockIdx.x * 64 + lane;
    const int h = blockIdx.y;                // uniform per block
    const int b = blockIdx.z;

    const float* xb = x + (size_t)b * (CCH * HWSZ);
    const float* xc = xb + (size_t)(cg * 16) * HWSZ;

    // Clamped neighbor offsets. h is block-uniform (scalar); w varies per lane.
    int hoff[5], woff[5];
    bool hin[5], win[5];
#pragma unroll
    for (int d = 0; d < 5; ++d) {
        int hh2 = h + d - 2;
        hin[d] = (hh2 >= 0) && (hh2 < HH);
        int hc = hh2 < 0 ? 0 : (hh2 > HH - 1 ? HH - 1 : hh2);
        hoff[d] = hc * WW;
        int ww2 = w + d - 2;
        win[d] = (ww2 >= 0) && (ww2 < WW);
        woff[d] = ww2 < 0 ? 0 : (ww2 > WW - 1 ? WW - 1 : ww2);
    }

    // ---- Phase 1: partial raw dots over this thread's 16 channels ----
    float D[25];
#pragma unroll
    for (int n = 0; n < 25; ++n) D[n] = 0.f;

#pragma unroll 4
    for (int c = 0; c < 16; ++c) {
        const float* pc = xc + c * HWSZ;
        float nb[25];
#pragma unroll
        for (int di = 0; di < 5; ++di) {
            const float* r = pc + hoff[di];
#pragma unroll
            for (int dj = 0; dj < 5; ++dj) {
                nb[di * 5 + dj] = r[woff[dj]];
            }
        }
        float cv = nb[12];
#pragma unroll
        for (int n = 0; n < 25; ++n) {
            D[n] = fmaf(cv, nb[n], D[n]);
        }
    }

    // ---- Reduce partial dots across the 4 channel groups ----
    __shared__ float red[3][64][27];   // pad 27: stride coprime with 32 banks
    __shared__ float sW[25][64];       // broadcast weights
    if (cg > 0) {
#pragma unroll
        for (int n = 0; n < 25; ++n) red[cg - 1][lane][n] = D[n];
    }
    __syncthreads();

    if (cg == 0) {
#pragma unroll
        for (int n = 0; n < 25; ++n) {
            D[n] += red[0][lane][n] + red[1][lane][n] + red[2][lane][n];
        }
        const int p = b * HWSZ + h * WW + w;
        const float s_p = s_arr[p];
        const float q_p = q_arr[p];
        const float N2c = fmaf(2.f * EPS, s_p, q_p) + CEPS2;

        float logit[25];
        float m = -1e30f;
#pragma unroll
        for (int di = 0; di < 5; ++di) {
#pragma unroll
            for (int dj = 0; dj < 5; ++dj) {
                const int n = di * 5 + dj;
                const bool inb = hin[di] && win[dj];
                const int qi = b * HWSZ + hoff[di] + woff[dj];
                const float s_q = inb ? s_arr[qi] : 0.f;
                const float q_q = inb ? q_arr[qi] : 0.f;
                const float Dn = (inb ? D[n] : 0.f) + EPS * (s_p + s_q) + CEPS2;
                const float N2n = fmaf(2.f * EPS, s_q, q_q) + CEPS2;
                const float sim = Dn * rsqrtf(N2n * N2c);
                const float t = TEMP * sim;
                logit[n] = t;
                m = fmaxf(m, t);
            }
        }
        float wei[25];
        float sum = 0.f;
#pragma unroll
        for (int n = 0; n < 25; ++n) {
            float e = __expf(logit[n] - m);
            wei[n] = e;
            sum += e;
        }
        const float rsum = 1.f / sum;
        // OOB neighbors stay in the softmax denominator but contribute only
        // the EPS constant to the output -> zero their weight for the x-sum.
#pragma unroll
        for (int di = 0; di < 5; ++di) {
#pragma unroll
            for (int dj = 0; dj < 5; ++dj) {
                const int n = di * 5 + dj;
                const float wn = (hin[di] && win[dj]) ? wei[n] * rsum : 0.f;
                sW[n][lane] = wn;
            }
        }
    }
    __syncthreads();

    float wv[25];
#pragma unroll
    for (int n = 0; n < 25; ++n) wv[n] = sW[n][lane];

    // ---- Phase 2: weighted sum for this thread's 16 channels ----
    const int outbase = h * WW + w;
#pragma unroll 4
    for (int c = 0; c < 16; ++c) {
        const float* pc = xc + c * HWSZ;
        float acc = EPS;
#pragma unroll
        for (int di = 0; di < 5; ++di) {
            const float* r = pc + hoff[di];
#pragma unroll
            for (int dj = 0; dj < 5; ++dj) {
                acc = fmaf(wv[di * 5 + dj], r[woff[dj]], acc);
            }
        }
        out[((size_t)b * CCH + cg * 16 + c) * HWSZ + outbase] = acc;
    }
}

extern "C" void kernel_launch(void* const* d_in, const int* in_sizes, int n_in,
                              void* d_out, int out_size, void* d_ws, size_t ws_size,
                              hipStream_t stream) {
    const float* x = (const float*)d_in[0];
    float* outp = (float*)d_out;
    float* s_arr = (float*)d_ws;
    float* q_arr = s_arr + 4 * HWSZ;

    rv_norms<<<dim3(WW / 64, HH, 4), dim3(64, 4, 1), 0, stream>>>(x, s_arr, q_arr);
    rv_fused<<<dim3(WW / 64, HH, 4), dim3(64, 4, 1), 0, stream>>>(x, s_arr, q_arr, outp);
}

// Round 3
// 110.555 us; speedup vs baseline: 1.8605x; 1.5921x over previous
//
#include <hip/hip_runtime.h>

#define EPS 1e-5f
#define TEMP 50.0f
#define CCH 64
#define HH 128
#define WW 128
#define HWSZ (HH * WW)
#define CEPS2 (CCH * EPS * EPS)

#define IT 8            // interior tile: 8x8 pixels
#define HT 12           // halo tile: 12x12
#define HPX (HT * HT)   // 144 halo pixels

// Single fully-fused kernel. Block: 256 threads = 4 channel-groups x 64 pixels.
// LDS: tile[g][px] = float4 of channels 4g..4g+3 at halo pixel px (zero-padded).
__global__ __launch_bounds__(256) void rv_fused(const float* __restrict__ x,
                                                float* __restrict__ out) {
    __shared__ float4 tile[16][HPX];        // 36864 B
    __shared__ float red[2][64][25];        // 12800 B  (partial dots, then weights)
    __shared__ float sh_s[HPX], sh_q[HPX];  // 1152 B

    const int t  = threadIdx.x;
    const int w0 = blockIdx.x * IT;
    const int h0 = blockIdx.y * IT;
    const int b  = blockIdx.z;
    const float* xb = x + (size_t)b * (CCH * HWSZ);

    // ---- Stage zero-padded halo: 64ch x 144px = 9216 floats, 36 iters ----
#pragma unroll 6
    for (int it = 0; it < 36; ++it) {
        int k = it * 256 + t;
        int c = k / HPX;              // constant divisor -> mul/shift
        int px = k - c * HPX;
        int row = px / HT;
        int col = px - row * HT;
        int gh = h0 + row - 2;
        int gw = w0 + col - 2;
        float v = 0.f;
        if (gh >= 0 && gh < HH && gw >= 0 && gw < WW)
            v = xb[c * HWSZ + gh * WW + gw];
        ((float*)&tile[c >> 2][px])[c & 3] = v;
    }
    __syncthreads();

    // ---- Per-halo-pixel norms: s = sum_c x, q = sum_c x^2 ----
    if (t < HPX) {
        float s = 0.f, q = 0.f;
#pragma unroll
        for (int g = 0; g < 16; ++g) {
            float4 v = tile[g][t];
            s += v.x + v.y + v.z + v.w;
            q = fmaf(v.x, v.x, q);
            q = fmaf(v.y, v.y, q);
            q = fmaf(v.z, v.z, q);
            q = fmaf(v.w, v.w, q);
        }
        sh_s[t] = s;
        sh_q[t] = q;
    }

    const int cg  = t >> 6;          // 0..3, 16 channels each
    const int pix = t & 63;
    const int r   = pix >> 3;
    const int col = pix & 7;
    const int cpx = (r + 2) * HT + (col + 2);

    // ---- Phase 1: partial raw dots over this cg's 16 channels ----
    float4 ctr[4];
#pragma unroll
    for (int g = 0; g < 4; ++g) ctr[g] = tile[cg * 4 + g][cpx];

    float D[25];
#pragma unroll
    for (int dr = 0; dr < 5; ++dr) {
#pragma unroll
        for (int dc = 0; dc < 5; ++dc) {
            const int npx = (r + dr) * HT + (col + dc);
            float d = 0.f;
#pragma unroll
            for (int g = 0; g < 4; ++g) {
                float4 v = tile[cg * 4 + g][npx];
                d = fmaf(ctr[g].x, v.x, d);
                d = fmaf(ctr[g].y, v.y, d);
                d = fmaf(ctr[g].z, v.z, d);
                d = fmaf(ctr[g].w, v.w, d);
            }
            D[dr * 5 + dc] = d;
        }
    }

    // ---- Reduce partial dots across 4 channel groups (2 rounds) ----
    if (cg >= 2) {
#pragma unroll
        for (int n = 0; n < 25; ++n) red[cg - 2][pix][n] = D[n];
    }
    __syncthreads();
    if (cg < 2) {
#pragma unroll
        for (int n = 0; n < 25; ++n) D[n] += red[cg][pix][n];
    }
    __syncthreads();
    if (cg == 1) {
#pragma unroll
        for (int n = 0; n < 25; ++n) red[0][pix][n] = D[n];
    }
    __syncthreads();

    // ---- Softmax (cg0 threads, one per pixel) ----
    if (cg == 0) {
        const float s_p = sh_s[cpx];
        const float q_p = sh_q[cpx];
        const float N2c = fmaf(2.f * EPS, s_p, q_p) + CEPS2;
        float logit[25];
        float m = -1e30f;
#pragma unroll
        for (int dr = 0; dr < 5; ++dr) {
#pragma unroll
            for (int dc = 0; dc < 5; ++dc) {
                const int n = dr * 5 + dc;
                const int npx = (r + dr) * HT + (col + dc);
                const float s_q = sh_s[npx];
                const float q_q = sh_q[npx];
                const float Dn = D[n] + red[0][pix][n] + EPS * (s_p + s_q) + CEPS2;
                const float N2n = fmaf(2.f * EPS, s_q, q_q) + CEPS2;
                const float sim = Dn * rsqrtf(N2n * N2c);
                logit[n] = TEMP * sim;
                m = fmaxf(m, logit[n]);
            }
        }
        float wei[25];
        float sum = 0.f;
#pragma unroll
        for (int n = 0; n < 25; ++n) {
            float e = __expf(logit[n] - m);
            wei[n] = e;
            sum += e;
        }
        const float rs = 1.f / sum;
        // OOB neighbors keep their weight: zero-padded tile means they
        // contribute exactly the +EPS constant, matching the reference.
#pragma unroll
        for (int n = 0; n < 25; ++n) red[0][pix][n] = wei[n] * rs;
    }
    __syncthreads();

    // ---- Phase 2: weighted sums for this cg's 16 channels ----
    float4 acc[4];
#pragma unroll
    for (int g = 0; g < 4; ++g) acc[g] = make_float4(EPS, EPS, EPS, EPS);
#pragma unroll
    for (int dr = 0; dr < 5; ++dr) {
#pragma unroll
        for (int dc = 0; dc < 5; ++dc) {
            const int npx = (r + dr) * HT + (col + dc);
            const float wn = red[0][pix][dr * 5 + dc];
#pragma unroll
            for (int g = 0; g < 4; ++g) {
                float4 v = tile[cg * 4 + g][npx];
                acc[g].x = fmaf(wn, v.x, acc[g].x);
                acc[g].y = fmaf(wn, v.y, acc[g].y);
                acc[g].z = fmaf(wn, v.z, acc[g].z);
                acc[g].w = fmaf(wn, v.w, acc[g].w);
            }
        }
    }

    const size_t obase = (size_t)b * (CCH * HWSZ) + (h0 + r) * WW + (w0 + col);
#pragma unroll
    for (int g = 0; g < 4; ++g) {
        const int c0 = cg * 16 + g * 4;
        out[obase + (size_t)(c0 + 0) * HWSZ] = acc[g].x;
        out[obase + (size_t)(c0 + 1) * HWSZ] = acc[g].y;
        out[obase + (size_t)(c0 + 2) * HWSZ] = acc[g].z;
        out[obase + (size_t)(c0 + 3) * HWSZ] = acc[g].w;
    }
}

extern "C" void kernel_launch(void* const* d_in, const int* in_sizes, int n_in,
                              void* d_out, int out_size, void* d_ws, size_t ws_size,
                              hipStream_t stream) {
    const float* x = (const float*)d_in[0];
    float* outp = (float*)d_out;
    rv_fused<<<dim3(WW / IT, HH / IT, 4), dim3(256, 1, 1), 0, stream>>>(x, outp);
}

// Round 4
// 98.386 us; speedup vs baseline: 2.0907x; 1.1237x over previous
//
#include <hip/hip_runtime.h>

#define EPS 1e-5f
#define TEMP 50.0f
#define CCH 64
#define HH 128
#define WW 128
#define HWSZ (HH * WW)
#define CEPS2 (CCH * EPS * EPS)

#define IT 8            // interior tile: 8x8 pixels
#define HT 12           // halo tile: 12x12  (do NOT pad: 8-lane row groups
                        // give conflict-free b128 reads at stride 12)
#define HPX (HT * HT)   // 144 halo pixels

// Single fully-fused kernel. Block: 256 threads = 4 channel-groups x 64 pixels.
// LDS: tile[q][px] = float4 of channels 4q..4q+3 at halo pixel px (zero-padded).
__global__ __launch_bounds__(256) void rv_fused(const float* __restrict__ x,
                                                float* __restrict__ out) {
    __shared__ float4 tile[16][HPX];        // 36864 B
    __shared__ float red[2][64][25];        // 12800 B  (partial dots, then weights)
    __shared__ float sh_s[HPX], sh_q[HPX];  // 1152 B

    const int t  = threadIdx.x;
    const int w0 = blockIdx.x * IT;
    const int h0 = blockIdx.y * IT;
    const int b  = blockIdx.z;
    const float* xb = x + (size_t)b * (CCH * HWSZ);

    // ---- Stage zero-padded halo: 16 quads x 144 px = 2304 float4, 9 iters.
    // Each thread: 4 coalesced global loads (one pixel, 4 consecutive channels)
    // -> one b128 LDS write at contiguous 16B lane stride (conflict-free).
#pragma unroll
    for (int it = 0; it < 9; ++it) {
        int k = it * 256 + t;         // 0..2303
        int c4 = k / HPX;             // quad 0..15 (const-div -> mul/shift)
        int px = k - c4 * HPX;
        int row = px / HT;
        int col = px - row * HT;
        int gh = h0 + row - 2;
        int gw = w0 + col - 2;
        float4 v = make_float4(0.f, 0.f, 0.f, 0.f);
        if (gh >= 0 && gh < HH && gw >= 0 && gw < WW) {
            const float* p = xb + (size_t)(c4 * 4) * HWSZ + gh * WW + gw;
            v.x = p[0];
            v.y = p[HWSZ];
            v.z = p[2 * HWSZ];
            v.w = p[3 * HWSZ];
        }
        tile[c4][px] = v;
    }
    __syncthreads();

    // ---- Per-halo-pixel norms: s = sum_c x, q = sum_c x^2 ----
    if (t < HPX) {
        float s = 0.f, q = 0.f;
#pragma unroll
        for (int g = 0; g < 16; ++g) {
            float4 v = tile[g][t];
            s += v.x + v.y + v.z + v.w;
            q = fmaf(v.x, v.x, q);
            q = fmaf(v.y, v.y, q);
            q = fmaf(v.z, v.z, q);
            q = fmaf(v.w, v.w, q);
        }
        sh_s[t] = s;
        sh_q[t] = q;
    }

    const int cg  = t >> 6;          // 0..3, 16 channels each
    const int pix = t & 63;
    const int r   = pix >> 3;
    const int col = pix & 7;
    const int cpx = (r + 2) * HT + (col + 2);

    // ---- Phase 1: partial raw dots over this cg's 16 channels ----
    float4 ctr[4];
#pragma unroll
    for (int g = 0; g < 4; ++g) ctr[g] = tile[cg * 4 + g][cpx];

    float D[25];
#pragma unroll
    for (int dr = 0; dr < 5; ++dr) {
#pragma unroll
        for (int dc = 0; dc < 5; ++dc) {
            const int npx = (r + dr) * HT + (col + dc);
            float d = 0.f;
#pragma unroll
            for (int g = 0; g < 4; ++g) {
                float4 v = tile[cg * 4 + g][npx];
                d = fmaf(ctr[g].x, v.x, d);
                d = fmaf(ctr[g].y, v.y, d);
                d = fmaf(ctr[g].z, v.z, d);
                d = fmaf(ctr[g].w, v.w, d);
            }
            D[dr * 5 + dc] = d;
        }
    }

    // ---- Reduce partial dots across 4 channel groups (2 rounds) ----
    if (cg >= 2) {
#pragma unroll
        for (int n = 0; n < 25; ++n) red[cg - 2][pix][n] = D[n];
    }
    __syncthreads();
    if (cg < 2) {
#pragma unroll
        for (int n = 0; n < 25; ++n) D[n] += red[cg][pix][n];
    }
    __syncthreads();
    if (cg == 1) {
#pragma unroll
        for (int n = 0; n < 25; ++n) red[0][pix][n] = D[n];
    }
    __syncthreads();

    // ---- Softmax (cg0 threads, one per pixel) ----
    if (cg == 0) {
        const float s_p = sh_s[cpx];
        const float q_p = sh_q[cpx];
        const float N2c = fmaf(2.f * EPS, s_p, q_p) + CEPS2;
        float logit[25];
        float m = -1e30f;
#pragma unroll
        for (int dr = 0; dr < 5; ++dr) {
#pragma unroll
            for (int dc = 0; dc < 5; ++dc) {
                const int n = dr * 5 + dc;
                const int npx = (r + dr) * HT + (col + dc);
                const float s_q = sh_s[npx];
                const float q_q = sh_q[npx];
                const float Dn = D[n] + red[0][pix][n] + EPS * (s_p + s_q) + CEPS2;
                const float N2n = fmaf(2.f * EPS, s_q, q_q) + CEPS2;
                const float sim = Dn * rsqrtf(N2n * N2c);
                logit[n] = TEMP * sim;
                m = fmaxf(m, logit[n]);
            }
        }
        float wei[25];
        float sum = 0.f;
#pragma unroll
        for (int n = 0; n < 25; ++n) {
            float e = __expf(logit[n] - m);
            wei[n] = e;
            sum += e;
        }
        const float rs = 1.f / sum;
        // OOB neighbors keep their weight: zero-padded tile means they
        // contribute exactly the +EPS constant, matching the reference.
#pragma unroll
        for (int n = 0; n < 25; ++n) red[0][pix][n] = wei[n] * rs;
    }
    __syncthreads();

    // ---- Phase 2: weighted sums for this cg's 16 channels ----
    float4 acc[4];
#pragma unroll
    for (int g = 0; g < 4; ++g) acc[g] = make_float4(EPS, EPS, EPS, EPS);
#pragma unroll
    for (int dr = 0; dr < 5; ++dr) {
#pragma unroll
        for (int dc = 0; dc < 5; ++dc) {
            const int npx = (r + dr) * HT + (col + dc);
            const float wn = red[0][pix][dr * 5 + dc];
#pragma unroll
            for (int g = 0; g < 4; ++g) {
                float4 v = tile[cg * 4 + g][npx];
                acc[g].x = fmaf(wn, v.x, acc[g].x);
                acc[g].y = fmaf(wn, v.y, acc[g].y);
                acc[g].z = fmaf(wn, v.z, acc[g].z);
                acc[g].w = fmaf(wn, v.w, acc[g].w);
            }
        }
    }

    const size_t obase = (size_t)b * (CCH * HWSZ) + (h0 + r) * WW + (w0 + col);
#pragma unroll
    for (int g = 0; g < 4; ++g) {
        const int c0 = cg * 16 + g * 4;
        out[obase + (size_t)(c0 + 0) * HWSZ] = acc[g].x;
        out[obase + (size_t)(c0 + 1) * HWSZ] = acc[g].y;
        out[obase + (size_t)(c0 + 2) * HWSZ] = acc[g].z;
        out[obase + (size_t)(c0 + 3) * HWSZ] = acc[g].w;
    }
}

extern "C" void kernel_launch(void* const* d_in, const int* in_sizes, int n_in,
                              void* d_out, int out_size, void* d_ws, size_t ws_size,
                              hipStream_t stream) {
    const float* x = (const float*)d_in[0];
    float* outp = (float*)d_out;
    rv_fused<<<dim3(WW / IT, HH / IT, 4), dim3(256, 1, 1), 0, stream>>>(x, outp);
}

// Round 5
// 89.405 us; speedup vs baseline: 2.3007x; 1.1005x over previous
//
#include <hip/hip_runtime.h>

#define EPS 1e-5f
#define TEMP 50.0f
#define CCH 64
#define HH 128
#define WW 128
#define HWSZ (HH * WW)
#define CEPS2 (CCH * EPS * EPS)

#define IT 8            // interior tile: 8x8 pixels
#define HT 12           // halo tile: 12x12 (unpadded: 8-lane row groups give
                        // conflict-free b128 access at 16B stride)
#define HPX (HT * HT)   // 144 halo pixels

typedef _Float16 h16;
typedef h16 h2v __attribute__((ext_vector_type(2)));
typedef h16 h8v __attribute__((ext_vector_type(8)));

union H8 { h8v v; h2v p[4]; };

__device__ __forceinline__ float fdot2(h2v a, h2v b, float c) {
#if __has_builtin(__builtin_amdgcn_fdot2)
    return __builtin_amdgcn_fdot2(a, b, c, false);   // v_dot2_f32_f16
#else
    return c + (float)a[0] * (float)b[0] + (float)a[1] * (float)b[1];
#endif
}

// Single fully-fused kernel. Block: 256 threads = 4 channel-groups x 64 pixels.
// LDS tile[hq][px] = 8 consecutive channels (f16) at halo pixel px, zero-padded.
__global__ __launch_bounds__(256) void rv_fused(const float* __restrict__ x,
                                                float* __restrict__ out) {
    __shared__ h8v  tile[8][HPX];           // 18432 B
    __shared__ float red[2][64][25];        // 12800 B (partial dots, then weights)
    __shared__ float sh_s[HPX], sh_q[HPX];  // 1152 B

    const int t  = threadIdx.x;
    const int w0 = blockIdx.x * IT;
    const int h0 = blockIdx.y * IT;
    const int b  = blockIdx.z;
    const float* xb = x + (size_t)b * (CCH * HWSZ);

    // ---- Stage: 8 half8-quads x 144 px = 1152 elements, 5 iters ----
#pragma unroll
    for (int it = 0; it < 5; ++it) {
        int k = it * 256 + t;
        if (k < 8 * HPX) {
            int hq = k / HPX;            // 0..7 (8 channels each)
            int px = k - hq * HPX;
            int row = px / HT;
            int col = px - row * HT;
            int gh = h0 + row - 2;
            int gw = w0 + col - 2;
            float vv[8] = {0.f, 0.f, 0.f, 0.f, 0.f, 0.f, 0.f, 0.f};
            if (gh >= 0 && gh < HH && gw >= 0 && gw < WW) {
                const float* p = xb + (size_t)(hq * 8) * HWSZ + gh * WW + gw;
#pragma unroll
                for (int j = 0; j < 8; ++j) vv[j] = p[j * HWSZ];
            }
            h8v hv;
#pragma unroll
            for (int j = 0; j < 8; ++j) hv[j] = (h16)vv[j];
            tile[hq][px] = hv;           // contiguous b128, conflict-free
        }
    }
    __syncthreads();

    // ---- Per-halo-pixel norms from the SAME rounded values (consistency) ----
    if (t < HPX) {
        float s = 0.f, q = 0.f;
        const h2v one2 = {(h16)1.f, (h16)1.f};
#pragma unroll
        for (int hq = 0; hq < 8; ++hq) {
            H8 u; u.v = tile[hq][t];
#pragma unroll
            for (int j = 0; j < 4; ++j) {
                s = fdot2(u.p[j], one2, s);
                q = fdot2(u.p[j], u.p[j], q);
            }
        }
        sh_s[t] = s;
        sh_q[t] = q;
    }
    // (visibility of sh_s/sh_q is covered by the reduction __syncthreads below)

    const int cg  = t >> 6;              // 0..3, 16 channels each (hq 2cg, 2cg+1)
    const int pix = t & 63;
    const int r   = pix >> 3;
    const int col = pix & 7;
    const int cpx = (r + 2) * HT + (col + 2);

    // ---- Phase 1: partial raw dots over this cg's 16 channels ----
    H8 c0, c1;
    c0.v = tile[cg * 2][cpx];
    c1.v = tile[cg * 2 + 1][cpx];

    float D[25];
#pragma unroll
    for (int dr = 0; dr < 5; ++dr) {
#pragma unroll
        for (int dc = 0; dc < 5; ++dc) {
            const int npx = (r + dr) * HT + (col + dc);
            H8 a0, a1;
            a0.v = tile[cg * 2][npx];
            a1.v = tile[cg * 2 + 1][npx];
            float d = 0.f;
#pragma unroll
            for (int j = 0; j < 4; ++j) d = fdot2(c0.p[j], a0.p[j], d);
#pragma unroll
            for (int j = 0; j < 4; ++j) d = fdot2(c1.p[j], a1.p[j], d);
            D[dr * 5 + dc] = d;
        }
    }

    // ---- Reduce partial dots across 4 channel groups (2 rounds) ----
    if (cg >= 2) {
#pragma unroll
        for (int n = 0; n < 25; ++n) red[cg - 2][pix][n] = D[n];
    }
    __syncthreads();
    if (cg < 2) {
#pragma unroll
        for (int n = 0; n < 25; ++n) D[n] += red[cg][pix][n];
    }
    __syncthreads();
    if (cg == 1) {
#pragma unroll
        for (int n = 0; n < 25; ++n) red[0][pix][n] = D[n];
    }
    __syncthreads();

    // ---- Softmax (cg0 threads, one per pixel) ----
    if (cg == 0) {
        const float s_p = sh_s[cpx];
        const float q_p = sh_q[cpx];
        const float N2c = fmaf(2.f * EPS, s_p, q_p) + CEPS2;
        float logit[25];
        float m = -1e30f;
#pragma unroll
        for (int dr = 0; dr < 5; ++dr) {
#pragma unroll
            for (int dc = 0; dc < 5; ++dc) {
                const int n = dr * 5 + dc;
                const int npx = (r + dr) * HT + (col + dc);
                const float s_q = sh_s[npx];
                const float q_q = sh_q[npx];
                const float Dn = D[n] + red[0][pix][n] + EPS * (s_p + s_q) + CEPS2;
                const float N2n = fmaf(2.f * EPS, s_q, q_q) + CEPS2;
                const float sim = Dn * rsqrtf(N2n * N2c);
                logit[n] = TEMP * sim;
                m = fmaxf(m, logit[n]);
            }
        }
        float wei[25];
        float sum = 0.f;
#pragma unroll
        for (int n = 0; n < 25; ++n) {
            float e = __expf(logit[n] - m);
            wei[n] = e;
            sum += e;
        }
        const float rs = 1.f / sum;
        // Zero-padded tile => OOB neighbors contribute exactly +EPS, matching ref.
#pragma unroll
        for (int n = 0; n < 25; ++n) red[0][pix][n] = wei[n] * rs;
    }
    __syncthreads();

    // ---- Phase 2: weighted sums for this cg's 16 channels ----
    float acc[16];
#pragma unroll
    for (int j = 0; j < 16; ++j) acc[j] = EPS;
#pragma unroll
    for (int dr = 0; dr < 5; ++dr) {
#pragma unroll
        for (int dc = 0; dc < 5; ++dc) {
            const int npx = (r + dr) * HT + (col + dc);
            const float wn = red[0][pix][dr * 5 + dc];
            H8 a0, a1;
            a0.v = tile[cg * 2][npx];
            a1.v = tile[cg * 2 + 1][npx];
#pragma unroll
            for (int j = 0; j < 8; ++j) {
                acc[j]     = fmaf(wn, (float)a0.v[j], acc[j]);
                acc[8 + j] = fmaf(wn, (float)a1.v[j], acc[8 + j]);
            }
        }
    }

    const size_t obase = (size_t)b * (CCH * HWSZ) + (h0 + r) * WW + (w0 + col);
#pragma unroll
    for (int j = 0; j < 16; ++j) {
        out[obase + (size_t)(cg * 16 + j) * HWSZ] = acc[j];
    }
}

extern "C" void kernel_launch(void* const* d_in, const int* in_sizes, int n_in,
                              void* d_out, int out_size, void* d_ws, size_t ws_size,
                              hipStream_t stream) {
    const float* x = (const float*)d_in[0];
    float* outp = (float*)d_out;
    rv_fused<<<dim3(WW / IT, HH / IT, 4), dim3(256, 1, 1), 0, stream>>>(x, outp);
}